// Round 23
// baseline (47.755 us; speedup 1.0000x reference)
//
#include <hip/hip_runtime.h>
#include <math.h>

#define CAP 64        // fixed edge slots per node; cnt>CAP takes the (never-hit) fallback
#define CSTRIDE 16    // one counter per 64B L2 line

#define LOG2E    1.44269504088896341f
#define LOG2E_3  0.48089834696298780f   // log2(e)/3

typedef float v2f __attribute__((ext_vector_type(2)));

__device__ __forceinline__ float celu3(float x) {
    return fmaxf(x, 0.0f) + 3.0f * (exp2f(fminf(x, 0.0f) * LOG2E_3) - 1.0f);
}
__device__ __forceinline__ v2f celu2(v2f x) {
    v2f zero = {0.f, 0.f};
    v2f pos = __builtin_elementwise_max(x, zero);
    v2f neg = __builtin_elementwise_min(x, zero);
    v2f targ = neg * LOG2E_3;
    v2f e;
    e.x = exp2f(targ.x);
    e.y = exp2f(targ.y);
    return (pos - 3.0f) + e * 3.0f;
}

template <int CTRL>
__device__ __forceinline__ float dpp_add(float v) {
    int o = __builtin_amdgcn_update_dpp(0, __float_as_int(v), CTRL, 0xf, 0xf, true);
    return v + __int_as_float(o);
}
template <int CTRL>
__device__ __forceinline__ float dpp_mov(float v) {
    int o = __builtin_amdgcn_update_dpp(0, __float_as_int(v), CTRL, 0xf, 0xf, true);
    return __int_as_float(o);
}
__device__ __forceinline__ float red16(float v) {
    v = dpp_add<0xB1>(v);
    v = dpp_add<0x4E>(v);
    v = dpp_add<0x124>(v);
    v = dpp_add<0x128>(v);
    return v;
}
__device__ __forceinline__ float wave_sum64(float v) {
    v = red16(v);
    v += __shfl_xor(v, 16, 64);
    v += __shfl_xor(v, 32, 64);
    return v;
}
__device__ __forceinline__ v2f xor_red2(v2f v) {
    v.x += __shfl_xor(v.x, 16); v.x += __shfl_xor(v.x, 32);
    v.y += __shfl_xor(v.y, 16); v.y += __shfl_xor(v.y, 32);
    return v;
}

// ---- K1: zero padded counts + a1 (one launch) ------------------------------

__global__ __launch_bounds__(256) void init_kernel(
    int* __restrict__ counts, int N,
    const float* __restrict__ feat, const float* __restrict__ w1,
    float* __restrict__ a1)
{
    int nz = N * CSTRIDE;
    int nblk_zero = (nz + 255) / 256;
    if ((int)blockIdx.x < nblk_zero) {
        int i = blockIdx.x * 256 + threadIdx.x;
        if (i < nz) counts[i] = 0;
        return;
    }
    int n = (blockIdx.x - nblk_zero) * 4 + (threadIdx.x >> 6);
    int lane = threadIdx.x & 63;
    if (n >= N) return;
    float f = feat[(long)n * 64 + lane];
    float s[4];
#pragma unroll
    for (int h = 0; h < 4; ++h) s[h] = wave_sum64(f * w1[h * 64 + lane]);
    if (lane < 4) a1[n * 4 + lane] = celu3(s[lane]);
}

// ---- K2: hist + direct slot scatter (padded counters) ----------------------

__global__ __launch_bounds__(256) void hist_kernel(
    const int* __restrict__ seg, int* __restrict__ counts,
    int* __restrict__ elist, int E)
{
    int i = blockIdx.x * 256 + threadIdx.x;
    int stride = gridDim.x * 256;
    for (; i < E; i += stride) {
        int s = seg[i];
        int r = atomicAdd(&counts[s * CSTRIDE], 1);
        if (r < CAP) elist[s * CAP + r] = i;
    }
}

// ---- K3: fused, TWO NODES PER WAVE (interleaved ILP) -----------------------
// One 64-thread block handles nodes (2b, 2b+1). The two nodes' chunk streams
// interleave in program order: node B's compute hides node A's gather latency
// (and vice versa) regardless of wave-scheduler behavior. Per-node math is
// r21's transposed-A/p + packed fp32. meta read exactly once.

__global__ __launch_bounds__(64) void fused_kernel(
    const float* __restrict__ meta, const float* __restrict__ w2,
    const float* __restrict__ a1, const int* __restrict__ counts,
    const int* __restrict__ elist, const int* __restrict__ seg,
    float* __restrict__ out, int N, int E)
{
    int lane = threadIdx.x;
    int n0 = blockIdx.x * 2;
    int n1 = n0 + 1;
    int g = lane >> 4;
    int q = lane & 15;
    int t = lane & 3;

    int cnt0 = counts[n0 * CSTRIDE];
    int cnt1 = (n1 < N) ? counts[n1 * CSTRIDE] : 0;

    if (cnt0 <= CAP && cnt1 <= CAP) {
        // shared weights (packed pairs)
        float4 w0 = *(const float4*)(w2 + 0 * 64 + q * 4);
        float4 w1v = *(const float4*)(w2 + 1 * 64 + q * 4);
        float4 wv2 = *(const float4*)(w2 + 2 * 64 + q * 4);
        float4 w3 = *(const float4*)(w2 + 3 * 64 + q * 4);
        v2f w0a = {w0.x, w0.y},  w0b = {w0.z, w0.w};
        v2f w1a = {w1v.x, w1v.y}, w1b = {w1v.z, w1v.w};
        v2f w2a = {wv2.x, wv2.y}, w2b = {wv2.z, wv2.w};
        v2f w3a = {w3.x, w3.y},  w3b = {w3.z, w3.w};

        float4 a1v0 = *(const float4*)(a1 + (long)n0 * 4);
        float a1s0 = (t == 0) ? a1v0.x : (t == 1) ? a1v0.y : (t == 2) ? a1v0.z : a1v0.w;
        float a1s1 = 0.f;
        if (n1 < N) {
            float4 a1v1 = *(const float4*)(a1 + (long)n1 * 4);
            a1s1 = (t == 0) ? a1v1.x : (t == 1) ? a1v1.y : (t == 2) ? a1v1.z : a1v1.w;
        }

        int eid_l0 = (lane < cnt0) ? elist[(long)n0 * CAP + lane] : 0;
        int eid_l1 = (lane < cnt1) ? elist[(long)n1 * CAP + lane] : 0;
        const float* meta_q = meta + q * 4;

        float sp0 = 0.f, sp1 = 0.f;
        v2f A0a = {0,0}, A0b = {0,0}, A1a = {0,0}, A1b = {0,0};
        v2f A2a = {0,0}, A2b = {0,0}, A3a = {0,0}, A3b = {0,0};
        v2f B0a = {0,0}, B0b = {0,0}, B1a = {0,0}, B1b = {0,0};
        v2f B2a = {0,0}, B2b = {0,0}, B3a = {0,0}, B3b = {0,0};

        int nch0 = (cnt0 + 3) >> 2;
        int nch1 = (cnt1 + 3) >> 2;
        int nchmax = nch0 > nch1 ? nch0 : nch1;

#pragma unroll 4
        for (int c = 0; c < nchmax; ++c) {
            int j = c * 4 + g;
            // ---- node 0 chunk (uniform guard) ----
            if (c < nch0) {
                bool vr = j < cnt0;
                int eid = __shfl(eid_l0, j);
                float4 v = *(const float4*)(meta_q + (long)eid * 64);
                v2f va = {v.x, v.y}, vb = {v.z, v.w};
                v2f efa = celu2(va), efb = celu2(vb);
                v2f pd0 = efa * w0a + efb * w0b;
                v2f pd1 = efa * w1a + efb * w1b;
                v2f pd2 = efa * w2a + efb * w2b;
                v2f pd3 = efa * w3a + efb * w3b;
                float d0 = pd0.x + pd0.y, d1 = pd1.x + pd1.y;
                float d2 = pd2.x + pd2.y, d3 = pd3.x + pd3.y;
                d0 = dpp_add<0xB1>(d0); d1 = dpp_add<0xB1>(d1);
                d2 = dpp_add<0xB1>(d2); d3 = dpp_add<0xB1>(d3);
                d0 = dpp_add<0x4E>(d0); d1 = dpp_add<0x4E>(d1);
                d2 = dpp_add<0x4E>(d2); d3 = dpp_add<0x4E>(d3);
                float dsel = (t == 0) ? d0 : (t == 1) ? d1 : (t == 2) ? d2 : d3;
                dsel = dpp_add<0x124>(dsel);
                dsel = dpp_add<0x128>(dsel);
                float A = vr ? celu3(a1s0 + dsel) : -INFINITY;
                float p = exp2f(fminf(A, 80.f) * LOG2E);
                sp0 += p;
                float b0 = dpp_mov<0x00>(p), b1 = dpp_mov<0x55>(p);
                float b2 = dpp_mov<0xAA>(p), b3 = dpp_mov<0xFF>(p);
                A0a += efa * b0; A0b += efb * b0;
                A1a += efa * b1; A1b += efb * b1;
                A2a += efa * b2; A2b += efb * b2;
                A3a += efa * b3; A3b += efb * b3;
            }
            // ---- node 1 chunk (uniform guard) ----
            if (c < nch1) {
                bool vr = j < cnt1;
                int eid = __shfl(eid_l1, j);
                float4 v = *(const float4*)(meta_q + (long)eid * 64);
                v2f va = {v.x, v.y}, vb = {v.z, v.w};
                v2f efa = celu2(va), efb = celu2(vb);
                v2f pd0 = efa * w0a + efb * w0b;
                v2f pd1 = efa * w1a + efb * w1b;
                v2f pd2 = efa * w2a + efb * w2b;
                v2f pd3 = efa * w3a + efb * w3b;
                float d0 = pd0.x + pd0.y, d1 = pd1.x + pd1.y;
                float d2 = pd2.x + pd2.y, d3 = pd3.x + pd3.y;
                d0 = dpp_add<0xB1>(d0); d1 = dpp_add<0xB1>(d1);
                d2 = dpp_add<0xB1>(d2); d3 = dpp_add<0xB1>(d3);
                d0 = dpp_add<0x4E>(d0); d1 = dpp_add<0x4E>(d1);
                d2 = dpp_add<0x4E>(d2); d3 = dpp_add<0x4E>(d3);
                float dsel = (t == 0) ? d0 : (t == 1) ? d1 : (t == 2) ? d2 : d3;
                dsel = dpp_add<0x124>(dsel);
                dsel = dpp_add<0x128>(dsel);
                float A = vr ? celu3(a1s1 + dsel) : -INFINITY;
                float p = exp2f(fminf(A, 80.f) * LOG2E);
                sp1 += p;
                float b0 = dpp_mov<0x00>(p), b1 = dpp_mov<0x55>(p);
                float b2 = dpp_mov<0xAA>(p), b3 = dpp_mov<0xFF>(p);
                B0a += efa * b0; B0b += efb * b0;
                B1a += efa * b1; B1b += efb * b1;
                B2a += efa * b2; B2b += efb * b2;
                B3a += efa * b3; B3b += efb * b3;
            }
        }

        // ---- epilogue node 0 ----
        {
            float sp = sp0;
            sp += __shfl_xor(sp, 16); sp += __shfl_xor(sp, 32);
            A0a = xor_red2(A0a); A0b = xor_red2(A0b);
            A1a = xor_red2(A1a); A1b = xor_red2(A1b);
            A2a = xor_red2(A2a); A2b = xor_red2(A2b);
            A3a = xor_red2(A3a); A3b = xor_red2(A3b);
            float spg = __int_as_float(__builtin_amdgcn_ds_bpermute(g << 2, __float_as_int(sp)));
            float rg = (cnt0 > 0) ? 1.f / spg : 0.f;
            v2f ava = (g == 0) ? A0a : (g == 1) ? A1a : (g == 2) ? A2a : A3a;
            v2f avb = (g == 0) ? A0b : (g == 1) ? A1b : (g == 2) ? A2b : A3b;
            float4 o;
            o.x = celu3(ava.x * rg); o.y = celu3(ava.y * rg);
            o.z = celu3(avb.x * rg); o.w = celu3(avb.y * rg);
            *(float4*)(out + (long)n0 * 256 + g * 64 + q * 4) = o;
        }
        // ---- epilogue node 1 ----
        if (n1 < N) {
            float sp = sp1;
            sp += __shfl_xor(sp, 16); sp += __shfl_xor(sp, 32);
            B0a = xor_red2(B0a); B0b = xor_red2(B0b);
            B1a = xor_red2(B1a); B1b = xor_red2(B1b);
            B2a = xor_red2(B2a); B2b = xor_red2(B2b);
            B3a = xor_red2(B3a); B3b = xor_red2(B3b);
            float spg = __int_as_float(__builtin_amdgcn_ds_bpermute(g << 2, __float_as_int(sp)));
            float rg = (cnt1 > 0) ? 1.f / spg : 0.f;
            v2f ava = (g == 0) ? B0a : (g == 1) ? B1a : (g == 2) ? B2a : B3a;
            v2f avb = (g == 0) ? B0b : (g == 1) ? B1b : (g == 2) ? B2b : B3b;
            float4 o;
            o.x = celu3(ava.x * rg); o.y = celu3(ava.y * rg);
            o.z = celu3(avb.x * rg); o.w = celu3(avb.y * rg);
            *(float4*)(out + (long)n1 * 256 + g * 64 + q * 4) = o;
        }
        return;
    }

    // ---- rare path (some cnt > CAP): brute-force seg scan per node ----
    for (int k = 0; k < 2; ++k) {
        int n = n0 + k;
        if (n >= N) continue;
        int cnt = counts[n * CSTRIDE];
        long ob2 = (long)n * 256 + lane;
        if (cnt == 0) {
            out[ob2] = 0.f; out[ob2 + 64] = 0.f;
            out[ob2 + 128] = 0.f; out[ob2 + 192] = 0.f;
            continue;
        }
        float4 a1v = *(const float4*)(a1 + (long)n * 4);
        float a10 = a1v.x, a11 = a1v.y, a12 = a1v.z, a13 = a1v.w;
        float w2v0 = w2[0 * 64 + lane], w2v1 = w2[1 * 64 + lane];
        float w2v2 = w2[2 * 64 + lane], w2v3 = w2[3 * 64 + lane];
        float m0 = -INFINITY, m1 = -INFINITY, m2 = -INFINITY, m3 = -INFINITY;
        float s0 = 0.f, s1 = 0.f, s2 = 0.f, s3 = 0.f;
        float ac0 = 0.f, ac1 = 0.f, ac2 = 0.f, ac3 = 0.f;
        for (int base = 0; base < E; base += 64) {
            int e = base + lane;
            bool hit = (e < E) && (seg[e] == n);
            unsigned long long ball = __ballot(hit);
            while (ball) {
                int b = __ffsll((long long)ball) - 1;
                ball &= ball - 1;
                int eid = base + b;
                float eft = celu3(meta[(long)eid * 64 + lane]);
                float d0 = wave_sum64(eft * w2v0);
                float d1 = wave_sum64(eft * w2v1);
                float d2 = wave_sum64(eft * w2v2);
                float d3 = wave_sum64(eft * w2v3);
                float A0 = celu3(a10 + d0), A1 = celu3(a11 + d1);
                float A2 = celu3(a12 + d2), A3 = celu3(a13 + d3);
                float nm0 = fmaxf(m0, A0), nm1 = fmaxf(m1, A1);
                float nm2 = fmaxf(m2, A2), nm3 = fmaxf(m3, A3);
                float al0 = __expf(m0 - nm0), al1 = __expf(m1 - nm1);
                float al2 = __expf(m2 - nm2), al3 = __expf(m3 - nm3);
                float p0 = __expf(A0 - nm0), p1 = __expf(A1 - nm1);
                float p2 = __expf(A2 - nm2), p3 = __expf(A3 - nm3);
                s0 = fmaf(al0, s0, p0); s1 = fmaf(al1, s1, p1);
                s2 = fmaf(al2, s2, p2); s3 = fmaf(al3, s3, p3);
                ac0 = fmaf(p0, eft, al0 * ac0); ac1 = fmaf(p1, eft, al1 * ac1);
                ac2 = fmaf(p2, eft, al2 * ac2); ac3 = fmaf(p3, eft, al3 * ac3);
                m0 = nm0; m1 = nm1; m2 = nm2; m3 = nm3;
            }
        }
        out[ob2]       = celu3(ac0 / s0);
        out[ob2 + 64]  = celu3(ac1 / s1);
        out[ob2 + 128] = celu3(ac2 / s2);
        out[ob2 + 192] = celu3(ac3 / s3);
    }
}

// ---- launch ----------------------------------------------------------------

extern "C" void kernel_launch(void* const* d_in, const int* in_sizes, int n_in,
                              void* d_out, int out_size, void* d_ws, size_t ws_size,
                              hipStream_t stream)
{
    const float* feat = (const float*)d_in[0];
    const float* meta = (const float*)d_in[1];
    const float* w1   = (const float*)d_in[2];
    const float* w2   = (const float*)d_in[3];
    const int*   seg  = (const int*)d_in[4];
    float* out = (float*)d_out;

    int N = in_sizes[0] / 64;
    int E = in_sizes[4];

    float* a1   = (float*)d_ws;                    // N*4 floats
    int* counts = (int*)(a1 + (size_t)N * 4);      // N*CSTRIDE ints (padded)
    int* elist  = counts + (size_t)N * CSTRIDE;    // N*CAP ints

    int nblk_zero = (N * CSTRIDE + 255) / 256;
    int nblk_a1   = (N + 3) / 4;

    init_kernel<<<nblk_zero + nblk_a1, 256, 0, stream>>>(counts, N, feat, w1, a1);
    hist_kernel<<<512, 256, 0, stream>>>(seg, counts, elist, E);
    fused_kernel<<<(N + 1) / 2, 64, 0, stream>>>(meta, w2, a1, counts, elist, seg, out, N, E);
}

// Round 24
// 44.791 us; speedup vs baseline: 1.0662x; 1.0662x over previous
//
#include <hip/hip_runtime.h>
#include <math.h>

#define CAP 64        // fixed edge slots per node; cnt>CAP takes the (never-hit) fallback
#define CSTRIDE 16    // one counter per 64B L2 line

#define LOG2E    1.44269504088896341f
#define LOG2E_3  0.48089834696298780f   // log2(e)/3

typedef float v2f __attribute__((ext_vector_type(2)));

__device__ __forceinline__ float celu3(float x) {
    // celu(x,3) = max(x,0) + 3*(2^(min(x,0)*log2e/3) - 1); exp2f = native v_exp_f32
    return fmaxf(x, 0.0f) + 3.0f * (exp2f(fminf(x, 0.0f) * LOG2E_3) - 1.0f);
}

// packed celu on 2 floats: max/min/mul/fma lower to v_pk_* on gfx950
__device__ __forceinline__ v2f celu2(v2f x) {
    v2f zero = {0.f, 0.f};
    v2f pos = __builtin_elementwise_max(x, zero);
    v2f neg = __builtin_elementwise_min(x, zero);
    v2f targ = neg * LOG2E_3;                 // v_pk_mul_f32
    v2f e;
    e.x = exp2f(targ.x);                      // scalar transcendental (not packable)
    e.y = exp2f(targ.y);
    return (pos - 3.0f) + e * 3.0f;           // v_pk_add + v_pk_fma
}

// DPP helpers: pure VALU, no LDS pipe on the chain. ctrl must be immediate.
template <int CTRL>
__device__ __forceinline__ float dpp_add(float v) {
    int o = __builtin_amdgcn_update_dpp(0, __float_as_int(v), CTRL, 0xf, 0xf, true);
    return v + __int_as_float(o);
}
template <int CTRL>
__device__ __forceinline__ float dpp_mov(float v) {
    int o = __builtin_amdgcn_update_dpp(0, __float_as_int(v), CTRL, 0xf, 0xf, true);
    return __int_as_float(o);
}
__device__ __forceinline__ float red16(float v) {
    v = dpp_add<0xB1>(v);    // quad_perm xor1
    v = dpp_add<0x4E>(v);    // quad_perm xor2
    v = dpp_add<0x124>(v);   // row_ror:4
    v = dpp_add<0x128>(v);   // row_ror:8
    return v;
}
__device__ __forceinline__ float wave_sum64(float v) {
    v = red16(v);
    v += __shfl_xor(v, 16, 64);
    v += __shfl_xor(v, 32, 64);
    return v;
}
__device__ __forceinline__ v2f xor_red2(v2f v) {
    v.x += __shfl_xor(v.x, 16); v.x += __shfl_xor(v.x, 32);
    v.y += __shfl_xor(v.y, 16); v.y += __shfl_xor(v.y, 32);
    return v;
}

// ---- K1: zero padded counts + a1 (one launch) ------------------------------

__global__ __launch_bounds__(256) void init_kernel(
    int* __restrict__ counts, int N,
    const float* __restrict__ feat, const float* __restrict__ w1,
    float* __restrict__ a1)
{
    int nz = N * CSTRIDE;
    int nblk_zero = (nz + 255) / 256;
    if ((int)blockIdx.x < nblk_zero) {
        int i = blockIdx.x * 256 + threadIdx.x;
        if (i < nz) counts[i] = 0;
        return;
    }
    int n = (blockIdx.x - nblk_zero) * 4 + (threadIdx.x >> 6);
    int lane = threadIdx.x & 63;
    if (n >= N) return;
    float f = feat[(long)n * 64 + lane];
    float s[4];
#pragma unroll
    for (int h = 0; h < 4; ++h) s[h] = wave_sum64(f * w1[h * 64 + lane]);
    if (lane < 4) a1[n * 4 + lane] = celu3(s[lane]);
}

// ---- K2: hist + direct slot scatter (padded counters) ----------------------

__global__ __launch_bounds__(256) void hist_kernel(
    const int* __restrict__ seg, int* __restrict__ counts,
    int* __restrict__ elist, int E)
{
    int i = blockIdx.x * 256 + threadIdx.x;
    int stride = gridDim.x * 256;
    for (; i < E; i += stride) {
        int s = seg[i];
        int r = atomicAdd(&counts[s * CSTRIDE], 1);
        if (r < CAP) elist[s * CAP + r] = i;
    }
}

// ---- K3: fused dots + fixed-shift softmax + aggregate ----------------------
// ONE WAVE PER BLOCK, one node per block. lane = (g = row-group, q = dim-quad,
// t = quad position = head). TRANSPOSED A/p (r18) + PACKED fp32 math (v_pk_*):
// celu/partial-dot/acc blocks run as 2-wide packed ops. meta read exactly once.

__global__ __launch_bounds__(64) void fused_kernel(
    const float* __restrict__ meta, const float* __restrict__ w2,
    const float* __restrict__ a1, const int* __restrict__ counts,
    const int* __restrict__ elist, const int* __restrict__ seg,
    float* __restrict__ out, int N, int E)
{
    int lane = threadIdx.x;
    int n = blockIdx.x;
    if (n >= N) return;

    int cnt = counts[n * CSTRIDE];
    int g = lane >> 4;       // row-group (gather) / head (store)
    int q = lane & 15;       // dim-quad
    int t = lane & 3;        // quad position = my head in the transposed compute
    long ob = (long)n * 256 + g * 64 + q * 4;

    if (cnt == 0) {
        float4 z = {0.f, 0.f, 0.f, 0.f};
        *(float4*)(out + ob) = z;
        return;
    }

    float4 a1v = *(const float4*)(a1 + (long)n * 4);

    if (cnt <= CAP) {
        // per-lane w2 slice as packed pairs: head h, dims 4q..4q+3
        float4 w0 = *(const float4*)(w2 + 0 * 64 + q * 4);
        float4 w1v = *(const float4*)(w2 + 1 * 64 + q * 4);
        float4 wv2 = *(const float4*)(w2 + 2 * 64 + q * 4);
        float4 w3 = *(const float4*)(w2 + 3 * 64 + q * 4);
        v2f w0a = {w0.x, w0.y},  w0b = {w0.z, w0.w};
        v2f w1a = {w1v.x, w1v.y}, w1b = {w1v.z, w1v.w};
        v2f w2a = {wv2.x, wv2.y}, w2b = {wv2.z, wv2.w};
        v2f w3a = {w3.x, w3.y},  w3b = {w3.z, w3.w};

        // hoisted: my head's a1
        float a1sel = (t == 0) ? a1v.x : (t == 1) ? a1v.y : (t == 2) ? a1v.z : a1v.w;

        int eid_l = (lane < cnt) ? elist[n * CAP + lane] : 0;
        const float* meta_q = meta + q * 4;

        float sp = 0.f;   // head-t partial denominator (per group)
        v2f acc0a = {0,0}, acc0b = {0,0}, acc1a = {0,0}, acc1b = {0,0};
        v2f acc2a = {0,0}, acc2b = {0,0}, acc3a = {0,0}, acc3b = {0,0};

        int nch = (cnt + 3) >> 2;
#pragma unroll 8
        for (int c = 0; c < nch; ++c) {
            int j = c * 4 + g;                 // my row this chunk (<=63)
            bool vr = j < cnt;
            int eid = __shfl(eid_l, j);
            float4 v = *(const float4*)(meta_q + (long)eid * 64);
            v2f va = {v.x, v.y}, vb = {v.z, v.w};
            v2f efa = celu2(va), efb = celu2(vb);

            // partial dots (packed), then horizontal add
            v2f pd0 = efa * w0a + efb * w0b;   // 2x v_pk ops
            v2f pd1 = efa * w1a + efb * w1b;
            v2f pd2 = efa * w2a + efb * w2b;
            v2f pd3 = efa * w3a + efb * w3b;
            float d0 = pd0.x + pd0.y;
            float d1 = pd1.x + pd1.y;
            float d2 = pd2.x + pd2.y;
            float d3 = pd3.x + pd3.y;

            // quad-level sums for all heads, then finish ONLY my head t
            d0 = dpp_add<0xB1>(d0); d1 = dpp_add<0xB1>(d1);
            d2 = dpp_add<0xB1>(d2); d3 = dpp_add<0xB1>(d3);
            d0 = dpp_add<0x4E>(d0); d1 = dpp_add<0x4E>(d1);
            d2 = dpp_add<0x4E>(d2); d3 = dpp_add<0x4E>(d3);
            float dsel = (t == 0) ? d0 : (t == 1) ? d1 : (t == 2) ? d2 : d3;
            dsel = dpp_add<0x124>(dsel);       // row_ror:4
            dsel = dpp_add<0x128>(dsel);       // row_ror:8 -> full 64-dim dot, head t

            // A/p once per lane (head t); p = 0 for invalid rows (exp2(-inf)=0)
            float A = vr ? celu3(a1sel + dsel) : -INFINITY;
            float p = exp2f(fminf(A, 80.f) * LOG2E);
            sp += p;

            // broadcast quad's 4 head-p values to all quad lanes
            float b0 = dpp_mov<0x00>(p);
            float b1 = dpp_mov<0x55>(p);
            float b2 = dpp_mov<0xAA>(p);
            float b3 = dpp_mov<0xFF>(p);

            // packed accumulate: 8 v_pk_fma vs 16 scalar fma
            acc0a += efa * b0; acc0b += efb * b0;
            acc1a += efa * b1; acc1b += efb * b1;
            acc2a += efa * b2; acc2b += efb * b2;
            acc3a += efa * b3; acc3b += efb * b3;
        }

        // sp: within a group, same-t lanes hold identical values; sum across groups
        sp += __shfl_xor(sp, 16); sp += __shfl_xor(sp, 32);

        // acc reduce across row-groups (xor 16, 32)
        acc0a = xor_red2(acc0a); acc0b = xor_red2(acc0b);
        acc1a = xor_red2(acc1a); acc1b = xor_red2(acc1b);
        acc2a = xor_red2(acc2a); acc2b = xor_red2(acc2b);
        acc3a = xor_red2(acc3a); acc3b = xor_red2(acc3b);

        float rg = 1.f / __int_as_float(__builtin_amdgcn_ds_bpermute(g << 2, __float_as_int(sp)));

        v2f ava = (g == 0) ? acc0a : (g == 1) ? acc1a : (g == 2) ? acc2a : acc3a;
        v2f avb = (g == 0) ? acc0b : (g == 1) ? acc1b : (g == 2) ? acc2b : acc3b;
        float4 o;
        o.x = celu3(ava.x * rg); o.y = celu3(ava.y * rg);
        o.z = celu3(avb.x * rg); o.w = celu3(avb.y * rg);
        *(float4*)(out + ob) = o;
        return;
    }

    // ---- fallback (cnt > CAP): brute-force seg scan, lane = dim. correct, never hot
    {
        float a10 = a1v.x, a11 = a1v.y, a12 = a1v.z, a13 = a1v.w;
        float w2v0 = w2[0 * 64 + lane], w2v1 = w2[1 * 64 + lane];
        float w2v2 = w2[2 * 64 + lane], w2v3 = w2[3 * 64 + lane];
        float m0 = -INFINITY, m1 = -INFINITY, m2 = -INFINITY, m3 = -INFINITY;
        float s0 = 0.f, s1 = 0.f, s2 = 0.f, s3 = 0.f;
        float ac0 = 0.f, ac1 = 0.f, ac2 = 0.f, ac3 = 0.f;
        for (int base = 0; base < E; base += 64) {
            int e = base + lane;
            bool hit = (e < E) && (seg[e] == n);
            unsigned long long ball = __ballot(hit);
            while (ball) {
                int b = __ffsll((long long)ball) - 1;
                ball &= ball - 1;
                int eid = base + b;
                float eft = celu3(meta[(long)eid * 64 + lane]);
                float d0 = wave_sum64(eft * w2v0);
                float d1 = wave_sum64(eft * w2v1);
                float d2 = wave_sum64(eft * w2v2);
                float d3 = wave_sum64(eft * w2v3);
                float A0 = celu3(a10 + d0), A1 = celu3(a11 + d1);
                float A2 = celu3(a12 + d2), A3 = celu3(a13 + d3);
                float nm0 = fmaxf(m0, A0), nm1 = fmaxf(m1, A1);
                float nm2 = fmaxf(m2, A2), nm3 = fmaxf(m3, A3);
                float al0 = __expf(m0 - nm0), al1 = __expf(m1 - nm1);
                float al2 = __expf(m2 - nm2), al3 = __expf(m3 - nm3);
                float p0 = __expf(A0 - nm0), p1 = __expf(A1 - nm1);
                float p2 = __expf(A2 - nm2), p3 = __expf(A3 - nm3);
                s0 = fmaf(al0, s0, p0); s1 = fmaf(al1, s1, p1);
                s2 = fmaf(al2, s2, p2); s3 = fmaf(al3, s3, p3);
                ac0 = fmaf(p0, eft, al0 * ac0); ac1 = fmaf(p1, eft, al1 * ac1);
                ac2 = fmaf(p2, eft, al2 * ac2); ac3 = fmaf(p3, eft, al3 * ac3);
                m0 = nm0; m1 = nm1; m2 = nm2; m3 = nm3;
            }
        }
        long ob2 = (long)n * 256 + lane;
        out[ob2]       = celu3(ac0 / s0);
        out[ob2 + 64]  = celu3(ac1 / s1);
        out[ob2 + 128] = celu3(ac2 / s2);
        out[ob2 + 192] = celu3(ac3 / s3);
    }
}

// ---- launch ----------------------------------------------------------------

extern "C" void kernel_launch(void* const* d_in, const int* in_sizes, int n_in,
                              void* d_out, int out_size, void* d_ws, size_t ws_size,
                              hipStream_t stream)
{
    const float* feat = (const float*)d_in[0];
    const float* meta = (const float*)d_in[1];
    const float* w1   = (const float*)d_in[2];
    const float* w2   = (const float*)d_in[3];
    const int*   seg  = (const int*)d_in[4];
    float* out = (float*)d_out;

    int N = in_sizes[0] / 64;
    int E = in_sizes[4];

    float* a1   = (float*)d_ws;                    // N*4 floats
    int* counts = (int*)(a1 + (size_t)N * 4);      // N*CSTRIDE ints (padded)
    int* elist  = counts + (size_t)N * CSTRIDE;    // N*CAP ints

    int nblk_zero = (N * CSTRIDE + 255) / 256;
    int nblk_a1   = (N + 3) / 4;

    init_kernel<<<nblk_zero + nblk_a1, 256, 0, stream>>>(counts, N, feat, w1, a1);
    hist_kernel<<<512, 256, 0, stream>>>(seg, counts, elist, E);
    fused_kernel<<<N, 64, 0, stream>>>(meta, w2, a1, counts, elist, seg, out, N, E);
}